// Round 20
// baseline (278.188 us; speedup 1.0000x reference)
//
#include <hip/hip_runtime.h>
#include <hip/hip_bf16.h>

typedef unsigned short u16;
typedef __attribute__((ext_vector_type(4))) float f32x4;
typedef __attribute__((ext_vector_type(16))) float f32x16;
typedef __attribute__((ext_vector_type(8))) short bf16x8;
typedef __attribute__((ext_vector_type(4))) short short4v;

#define B_N 8192
#define D_N 8000
#define H_N 100
#define V_N 8000
#define NG  512    // padded 4H
#define NKT 256    // K-steps of 32: 8192 total K (8000 x + 100 hidden + 92 pad)
#define TW  192    // tail width (hidden 100 + 92 zeros)

typedef const __attribute__((address_space(1))) unsigned int* gp_t;
typedef __attribute__((address_space(3))) unsigned int* lp_t;

static __device__ __forceinline__ short f2bf(float f) {
  unsigned u;
  __builtin_memcpy(&u, &f, 4);
  u = (u + 0x7fffu + ((u >> 16) & 1u)) >> 16;   // RNE
  return (short)u;
}
static __device__ __forceinline__ float bf2f(u16 b) {
  unsigned u = ((unsigned)b) << 16;
  float f;
  __builtin_memcpy(&f, &u, 4);
  return f;
}

// ---------------- pack hidden -> tail f32 [B_N][TW] (hidden | zeros) --------
__global__ __launch_bounds__(256) void pack_tail_kernel(
    const float* __restrict__ hidden, float* __restrict__ tail) {
  int idx = blockIdx.x * 256 + threadIdx.x;       // over B_N*24 chunks of 8
  if (idx >= B_N * 24) return;
  int b = idx / 24, c8 = (idx - b * 24) * 8;
  float o[8];
  if (c8 + 8 <= H_N) {
    const float* ph = hidden + (size_t)b * H_N + c8;
#pragma unroll
    for (int j = 0; j < 8; ++j) o[j] = ph[j];
  } else {
#pragma unroll
    for (int j = 0; j < 8; ++j) {
      int c = c8 + j;
      o[j] = (c < H_N) ? hidden[(size_t)b * H_N + c] : 0.f;
    }
  }
  f32x4 v0, v1;
#pragma unroll
  for (int j = 0; j < 4; ++j) { v0[j] = o[j]; v1[j] = o[4 + j]; }
  *(f32x4*)(tail + (size_t)b * TW + c8) = v0;
  *(f32x4*)(tail + (size_t)b * TW + c8 + 4) = v1;
}

// ---------------- pack U|W -> Wc, gld-linear physical order -----------------
__global__ __launch_bounds__(256) void pack_w_kernel(
    const float* __restrict__ U0, const float* __restrict__ U1,
    const float* __restrict__ U2, const float* __restrict__ U3,
    const float* __restrict__ W0, const float* __restrict__ W1,
    const float* __restrict__ W2, const float* __restrict__ W3,
    u16* __restrict__ Wc) {
  int idx = blockIdx.x * 256 + threadIdx.x;
  if (idx >= NKT * 2048) return;
  int t = idx >> 11;
  int j = idx & 2047;
  int pair = j >> 3, p = j & 7;
  int pl = p ^ (pair & 7);
  int n = pair * 2 + (pl >> 2);
  int s = pl & 3;
  int k0 = t * 32 + s * 8;
  bf16x8 ov;
  if (n >= 400) {
#pragma unroll
    for (int e = 0; e < 8; ++e) ov[e] = 0;
  } else {
    int g = n / 100;
    int r = n - g * 100;
    const float* U = (g == 0) ? U0 : (g == 1) ? U1 : (g == 2) ? U2 : U3;
    const float* W = (g == 0) ? W0 : (g == 1) ? W1 : (g == 2) ? W2 : W3;
    if (k0 + 8 <= D_N) {
      const float* pu = U + (size_t)r * D_N + k0;
      f32x4 v0 = *(const f32x4*)pu;
      f32x4 v1 = *(const f32x4*)(pu + 4);
#pragma unroll
      for (int e = 0; e < 4; ++e) { ov[e] = f2bf(v0[e]); ov[4 + e] = f2bf(v1[e]); }
    } else {
#pragma unroll
      for (int e = 0; e < 8; ++e) {
        int col = k0 + e - D_N;
        ov[e] = (col >= 0 && col < H_N) ? f2bf(W[(size_t)r * H_N + col]) : (short)0;
      }
    }
  }
  *(bf16x8*)(Wc + (size_t)idx * 8) = ov;
}

// ---------------- pack V_w -> V2, MFMA-native layout ------------------------
__global__ __launch_bounds__(256) void pack_vw_kernel(
    const float* __restrict__ Vw, u16* __restrict__ V2) {
  int idx = blockIdx.x * 256 + threadIdx.x;
  if (idx >= 500 * 256) return;
  int n16 = idx >> 8, r = idx & 255;
  int kk = r >> 6, q = r & 63;
  int h = q >> 4, lr = q & 15;
  int n = n16 * 16 + lr;
  int k0 = kk * 32 + h * 8;
  bf16x8 ov;
#pragma unroll
  for (int e = 0; e < 8; ++e) {
    int col = k0 + e;
    ov[e] = (col < H_N) ? f2bf(Vw[(size_t)n * H_N + col]) : (short)0;
  }
  *(bf16x8*)(V2 + (size_t)idx * 8) = ov;
}

// ---------------- gates GEMM: BM=64, BN=256, BK=32, splitK=4 ----------------
// OCCUPANCY build (R19 bug fixed: As restored to full 64x32 tile = 2048 u16;
// R19 had halved it, overflowing As[0]->As[1]->Bs). LDS = 40 KB -> up to
// 4 blocks/CU by LDS; launch_bounds(512,6) -> 24 waves/CU (1.5x R13).
// bn-pair sharing an A-slice sits 8 bids apart (same XCD) -> 2nd x-read
// L2-hits. Schedule = R13 drain-only body (race-free by construction).
__global__ __launch_bounds__(512, 6) void gates_gemm_kernel(
    const float* __restrict__ x, const float* __restrict__ tail,
    const u16* __restrict__ Wc, u16* __restrict__ Cp) {
  __shared__ __align__(16) u16 As[2][2048];     // 4 KB each (64 rows x 32 k)
  __shared__ __align__(16) u16 Bs[2][8192];     // 16 KB each, pre-swizzled src
  const int t = threadIdx.x;
  const int w = t >> 6, l = t & 63;
  const int bid = blockIdx.x;
  const int xcd = bid & 7;
  const int kz = xcd >> 1;
  const int rest = bid >> 3;                      // 0..127
  const int bn = rest & 1;
  const int bm = (rest >> 1) | ((xcd & 1) << 6);  // 0..127, bijective w/ kz,bn
  const int t0 = kz * 64;
  const int tmax = t0 + 63;
  const size_t bnoff = (size_t)bn * 8192;         // u16 offset of N-half in tile

  const int arow = t >> 3, ao = t & 7;
  const float* xrow = x + (size_t)(bm * 64 + arow) * D_N + ao * 4;
  const float* trow = tail + (size_t)(bm * 64 + arow) * TW + ao * 4;
  const int apair = arow >> 1;
  const int awr = apair * 64 + ((((arow & 1) << 2) | (ao >> 1)) ^ (apair & 7)) * 8
                  + (ao & 1) * 4;  // u16 units

  // wave tile: rows (w>>2)*32, cols (w&3)*64 (2 ni of 32)
  const int wm = (w >> 2) * 32, wnl = (w & 3) * 64;
  int aoff[2], boff[2][2];
#pragma unroll
  for (int kk = 0; kk < 2; ++kk) {
    int sa = kk * 2 + (l >> 5);
    int rowa = wm + (l & 31);
    int pa = rowa >> 1;
    aoff[kk] = pa * 64 + ((((rowa & 1) << 2) | sa) ^ (pa & 7)) * 8;
#pragma unroll
    for (int i = 0; i < 2; ++i) {
      int rowb = wnl + i * 32 + (l & 31);        // local row in 256-half
      int pb = rowb >> 1;                        // pb&7 == global pair &7
      boff[kk][i] = pb * 64 + ((((rowb & 1) << 2) | sa) ^ (pb & 7)) * 8;
    }
  }

  f32x16 acc0 = (f32x16)0.f, acc1 = (f32x16)0.f;

#define ASRC(tt) ((tt) < 250 ? xrow + (size_t)(tt) * 32 : trow + (size_t)((tt) - 250) * 32)
#define GLD_B(tt, buf)                                                         \
  _Pragma("unroll") for (int q = 0; q < 2; ++q)                                \
      __builtin_amdgcn_global_load_lds(                                        \
          (gp_t)(const void*)(Wc + (size_t)(tt) * 16384 + bnoff +              \
                              (size_t)(t + q * 512) * 8),                      \
          (lp_t)(void*)((u16*)Bs[buf] + (t + q * 512) * 8), 16, 0, 0);
#define DSW_A(buf, rv)                                                         \
  {                                                                            \
    short4v wv;                                                                \
    wv[0] = f2bf(rv[0]); wv[1] = f2bf(rv[1]);                                  \
    wv[2] = f2bf(rv[2]); wv[3] = f2bf(rv[3]);                                  \
    *(short4v*)((u16*)As[buf] + awr) = wv;                                     \
  }
#define COMPUTE(buf)                                                           \
  _Pragma("unroll") for (int kk = 0; kk < 2; ++kk) {                           \
    bf16x8 af = *(const bf16x8*)((const u16*)As[buf] + aoff[kk]);              \
    bf16x8 bv0 = *(const bf16x8*)((const u16*)Bs[buf] + boff[kk][0]);          \
    bf16x8 bv1 = *(const bf16x8*)((const u16*)Bs[buf] + boff[kk][1]);          \
    acc0 = __builtin_amdgcn_mfma_f32_32x32x16_bf16(af, bv0, acc0, 0, 0, 0);    \
    acc1 = __builtin_amdgcn_mfma_f32_32x32x16_bf16(af, bv1, acc1, 0, 0, 0);    \
  }
#define BODY(CB, tc)                                                           \
  {                                                                            \
    int tn = (tc) + 1 > tmax ? tmax : (tc) + 1;                                \
    GLD_B(tn, (CB) ^ 1);                                                       \
    ra = *(const f32x4*)ASRC(tn);                                              \
    __builtin_amdgcn_sched_barrier(0);                                         \
    COMPUTE(CB);                                                               \
    __builtin_amdgcn_sched_barrier(0);                                         \
    asm volatile("s_waitcnt vmcnt(0)" ::: "memory");                           \
    __builtin_amdgcn_sched_barrier(0);                                         \
    DSW_A((CB) ^ 1, ra);                                                       \
    asm volatile("s_waitcnt lgkmcnt(0)" ::: "memory");                         \
    __builtin_amdgcn_s_barrier();                                              \
  }

  // Prologue: stage tile t0 into buf0, full drain, barrier.
  f32x4 ra;
  {
    f32x4 r0 = *(const f32x4*)ASRC(t0);
    GLD_B(t0, 0);
    asm volatile("s_waitcnt vmcnt(0)" ::: "memory");
    DSW_A(0, r0);
    asm volatile("s_waitcnt lgkmcnt(0)" ::: "memory");
    __builtin_amdgcn_s_barrier();
  }

  for (int tt = t0; tt < t0 + 64; tt += 2) {
    BODY(0, tt);
    BODY(1, tt + 1);
  }

  // epilogue: store acc to bf16 partial buffer kz
  u16* Cg = Cp + (size_t)kz * B_N * NG;
  const int lcol = l & 31, lhi = (l >> 5) * 4;
#pragma unroll
  for (int ni = 0; ni < 2; ++ni) {
    f32x16 a = ni == 0 ? acc0 : acc1;
#pragma unroll
    for (int reg = 0; reg < 16; ++reg) {
      int row = bm * 64 + wm + (reg & 3) + 8 * (reg >> 2) + lhi;
      int col = bn * 256 + wnl + ni * 32 + lcol;
      Cg[(size_t)row * NG + col] = (u16)f2bf(a[reg]);
    }
  }
#undef BODY
#undef COMPUTE
#undef DSW_A
#undef GLD_B
#undef ASRC
}

// ---------------- fused act + logits + log_softmax (exact R13 version) ------
__global__ __launch_bounds__(1024, 4) void logits_lsm_kernel(
    const u16* __restrict__ gp, const float* __restrict__ c_in,
    const float* __restrict__ biu, const float* __restrict__ bfu,
    const float* __restrict__ bou, const float* __restrict__ bgu,
    const float* __restrict__ biw, const float* __restrict__ bfw,
    const float* __restrict__ bow, const float* __restrict__ bgw,
    const u16* __restrict__ V2, const float* __restrict__ Vb,
    float* __restrict__ h_out, float* __restrict__ c_out,
    float* __restrict__ out) {
  __shared__ u16 hs[32][128];
  __shared__ float red[16][32];
  __shared__ float lse_s[32];
  int t = threadIdx.x, w = t >> 6, l = t & 63;
  int lr = l & 15, hq = l >> 4;
  int rowbase = blockIdx.x * 32;

  // ---- phase 0: LSTM pointwise for our 32 rows ----
  if (t < 32 * 28) hs[t / 28][100 + t % 28] = 0;
  const size_t st = (size_t)B_N * NG;
  for (int i = t; i < 3200; i += 1024) {
    int b = i / 100, r = i - b * 100;
    int row = rowbase + b;
    const u16* g0 = gp + (size_t)row * NG;
    float gi = bf2f(g0[r]) + bf2f(g0[r + st]) + bf2f(g0[r + 2 * st]) +
               bf2f(g0[r + 3 * st]) + biu[r] + biw[r];
    float gf = bf2f(g0[r + 100]) + bf2f(g0[r + 100 + st]) +
               bf2f(g0[r + 100 + 2 * st]) + bf2f(g0[r + 100 + 3 * st]) +
               bfu[r] + bfw[r];
    float go = bf2f(g0[r + 200]) + bf2f(g0[r + 200 + st]) +
               bf2f(g0[r + 200 + 2 * st]) + bf2f(g0[r + 200 + 3 * st]) +
               bou[r] + bow[r];
    float gg = bf2f(g0[r + 300]) + bf2f(g0[r + 300 + st]) +
               bf2f(g0[r + 300 + 2 * st]) + bf2f(g0[r + 300 + 3 * st]) +
               bgu[r] + bgw[r];
    float it = 1.f / (1.f + __expf(-gi));
    float ft = 1.f / (1.f + __expf(-gf));
    float ot = 1.f / (1.f + __expf(-go));
    float gt = tanhf(gg);
    float ct = c_in[(size_t)row * H_N + r] * ft + gt * it;
    float ht = tanhf(ct) * ot;
    h_out[(size_t)row * H_N + r] = ht;
    c_out[(size_t)row * H_N + r] = ct;
    hs[b][r] = (u16)f2bf(ht);
  }
  __syncthreads();

  bf16x8 hf[2][4];
#pragma unroll
  for (int mi = 0; mi < 2; ++mi)
#pragma unroll
    for (int kk = 0; kk < 4; ++kk)
      hf[mi][kk] = *(const bf16x8*)(&hs[mi * 16 + lr][kk * 32 + hq * 8]);

// vp points at this wave's 64-col group; frag (ni,kk) at vp + (ni*4+kk)*512
#define VLD(vp, ni, kk) (*(const bf16x8*)((vp) + ((ni) * 4 + (kk)) * 512))
#define MF(accv, buf, kk)                                                      \
  _Pragma("unroll") for (int ni = 0; ni < 4; ++ni) {                           \
    accv[0][ni] = __builtin_amdgcn_mfma_f32_16x16x32_bf16(                     \
        hf[0][kk], buf[ni], accv[0][ni], 0, 0, 0);                             \
    accv[1][ni] = __builtin_amdgcn_mfma_f32_16x16x32_bf16(                     \
        hf[1][kk], buf[ni], accv[1][ni], 0, 0, 0);                             \
  }
#define GEMM_TILE(accv, vp)                                                    \
  {                                                                            \
    bf16x8 va[4], vbu[4];                                                      \
    _Pragma("unroll") for (int ni = 0; ni < 4; ++ni) va[ni] = VLD(vp, ni, 0);  \
    _Pragma("unroll") for (int ni = 0; ni < 4; ++ni) vbu[ni] = VLD(vp, ni, 1); \
    MF(accv, va, 0)                                                            \
    _Pragma("unroll") for (int ni = 0; ni < 4; ++ni) va[ni] = VLD(vp, ni, 2);  \
    MF(accv, vbu, 1)                                                           \
    _Pragma("unroll") for (int ni = 0; ni < 4; ++ni) vbu[ni] = VLD(vp, ni, 3); \
    MF(accv, va, 2)                                                            \
    MF(accv, vbu, 3)                                                           \
  }

  float s[8];
#pragma unroll
  for (int r = 0; r < 8; ++r) s[r] = 0.f;

  // ---- pass 1: sum of exp(logit - 8) ----
  for (int c = 0; c < 8; ++c) {
    int colbase = c * 1024 + w * 64;
    if (colbase >= V_N) continue;
    const u16* vp = V2 + (size_t)(colbase >> 4) * 2048 + l * 8;
    f32x4 acc[2][4];
#pragma unroll
    for (int mi = 0; mi < 2; ++mi)
#pragma unroll
      for (int ni = 0; ni < 4; ++ni) acc[mi][ni] = (f32x4)0.f;
    GEMM_TILE(acc, vp)
    float vb[4];
#pragma unroll
    for (int ni = 0; ni < 4; ++ni) vb[ni] = Vb[colbase + ni * 16 + lr];
#pragma unroll
    for (int r = 0; r < 8; ++r) {
      int mi = r >> 2, j = r & 3;
      float e = 0.f;
#pragma unroll
      for (int ni = 0; ni < 4; ++ni)
        e += __expf(acc[mi][ni][j] + vb[ni] - 8.f);
      s[r] += e;
    }
  }
#pragma unroll
  for (int off = 1; off < 16; off <<= 1)
#pragma unroll
    for (int r = 0; r < 8; ++r) s[r] += __shfl_xor(s[r], off, 64);

  if (lr == 0) {
#pragma unroll
    for (int r = 0; r < 8; ++r)
      red[w][(r >> 2) * 16 + hq * 4 + (r & 3)] = s[r];
  }
  __syncthreads();
  if (t < 32) {
    float S = 0.f;
#pragma unroll
    for (int ww = 0; ww < 16; ++ww) S += red[ww][t];
    lse_s[t] = 8.f + __logf(S);
  }
  __syncthreads();
  float lse_r[8];
#pragma unroll
  for (int r = 0; r < 8; ++r)
    lse_r[r] = lse_s[(r >> 2) * 16 + hq * 4 + (r & 3)];

  // ---- pass 2: recompute, subtract, store ----
  for (int c = 0; c < 8; ++c) {
    int colbase = c * 1024 + w * 64;
    if (colbase >= V_N) continue;
    const u16* vp = V2 + (size_t)(colbase >> 4) * 2048 + l * 8;
    f32x4 acc[2][4];
#pragma unroll
    for (int mi = 0; mi < 2; ++mi)
#pragma unroll
      for (int ni = 0; ni < 4; ++ni) acc[mi][ni] = (f32x4)0.f;
    GEMM_TILE(acc, vp)
    float vb[4];
#pragma unroll
    for (int ni = 0; ni < 4; ++ni) vb[ni] = Vb[colbase + ni * 16 + lr];
#pragma unroll
    for (int mi = 0; mi < 2; ++mi)
#pragma unroll
      for (int j = 0; j < 4; ++j) {
        size_t gr = (size_t)(rowbase + mi * 16 + hq * 4 + j);
#pragma unroll
        for (int ni = 0; ni < 4; ++ni)
          out[gr * V_N + colbase + ni * 16 + lr] =
              acc[mi][ni][j] + vb[ni] - lse_r[mi * 4 + j];
      }
  }
#undef GEMM_TILE
#undef MF
#undef VLD
}

extern "C" void kernel_launch(void* const* d_in, const int* in_sizes, int n_in,
                              void* d_out, int out_size, void* d_ws,
                              size_t ws_size, hipStream_t stream) {
  const float* x      = (const float*)d_in[0];
  const float* hidden = (const float*)d_in[1];
  const float* c_in   = (const float*)d_in[2];
  const float* Ui = (const float*)d_in[3];
  const float* Uf = (const float*)d_in[4];
  const float* Uo = (const float*)d_in[5];
  const float* Ug = (const float*)d_in[6];
  const float* Wi = (const float*)d_in[7];
  const float* Wf = (const float*)d_in[8];
  const float* Wo = (const float*)d_in[9];
  const float* Wg = (const float*)d_in[10];
  const float* Vw = (const float*)d_in[11];
  const float* Uib = (const float*)d_in[12];
  const float* Ufb = (const float*)d_in[13];
  const float* Uob = (const float*)d_in[14];
  const float* Ugb = (const float*)d_in[15];
  const float* Wib = (const float*)d_in[16];
  const float* Wfb = (const float*)d_in[17];
  const float* Wob = (const float*)d_in[18];
  const float* Wgb = (const float*)d_in[19];
  const float* Vb  = (const float*)d_in[20];

  float* out   = (float*)d_out;
  float* h_out = out + (size_t)B_N * V_N;
  float* c_out = h_out + (size_t)B_N * H_N;

  char* ws = (char*)d_ws;
  float* tailf = (float*)ws;  ws += (size_t)B_N * TW * 4;        // 6.3 MB
  u16* Wc = (u16*)ws;         ws += (size_t)NKT * 2048 * 16;     // 8.4 MB
  u16* V2 = (u16*)ws;         ws += (size_t)500 * 256 * 16;      // 2.0 MB
  u16* gates_p = (u16*)ws;    ws += (size_t)4 * B_N * NG * 2;    // 33.6 MB

  pack_tail_kernel<<<dim3(768), dim3(256), 0, stream>>>(hidden, tailf);
  pack_w_kernel<<<dim3(2048), dim3(256), 0, stream>>>(Ui, Uf, Uo, Ug,
                                                      Wi, Wf, Wo, Wg, Wc);
  pack_vw_kernel<<<dim3(500), dim3(256), 0, stream>>>(Vw, V2);

  gates_gemm_kernel<<<dim3(1024), dim3(512), 0, stream>>>(
      x, tailf, Wc, gates_p);

  logits_lsm_kernel<<<dim3(256), dim3(1024), 0, stream>>>(
      gates_p, c_in, Uib, Ufb, Uob, Ugb, Wib, Wfb, Wob, Wgb,
      V2, Vb, h_out, c_out, out);
}

// Round 21
// 220.147 us; speedup vs baseline: 1.2636x; 1.2636x over previous
//
#include <hip/hip_runtime.h>
#include <hip/hip_bf16.h>

typedef unsigned short u16;
typedef __attribute__((ext_vector_type(4))) float f32x4;
typedef __attribute__((ext_vector_type(16))) float f32x16;
typedef __attribute__((ext_vector_type(8))) short bf16x8;
typedef __attribute__((ext_vector_type(4))) short short4v;

#define B_N 8192
#define D_N 8000
#define H_N 100
#define V_N 8000
#define NG  512    // padded 4H
#define NKT 256    // K-steps of 32: 8192 total K (8000 x + 100 hidden + 92 pad)
#define TW  192    // tail width (hidden 100 + 92 zeros)

typedef const __attribute__((address_space(1))) unsigned int* gp_t;
typedef __attribute__((address_space(3))) unsigned int* lp_t;

static __device__ __forceinline__ short f2bf(float f) {
  unsigned u;
  __builtin_memcpy(&u, &f, 4);
  u = (u + 0x7fffu + ((u >> 16) & 1u)) >> 16;   // RNE
  return (short)u;
}
static __device__ __forceinline__ float bf2f(u16 b) {
  unsigned u = ((unsigned)b) << 16;
  float f;
  __builtin_memcpy(&f, &u, 4);
  return f;
}

// ---------------- pack hidden -> tail f32 [B_N][TW] (hidden | zeros) --------
__global__ __launch_bounds__(256) void pack_tail_kernel(
    const float* __restrict__ hidden, float* __restrict__ tail) {
  int idx = blockIdx.x * 256 + threadIdx.x;       // over B_N*24 chunks of 8
  if (idx >= B_N * 24) return;
  int b = idx / 24, c8 = (idx - b * 24) * 8;
  float o[8];
  if (c8 + 8 <= H_N) {
    const float* ph = hidden + (size_t)b * H_N + c8;
#pragma unroll
    for (int j = 0; j < 8; ++j) o[j] = ph[j];
  } else {
#pragma unroll
    for (int j = 0; j < 8; ++j) {
      int c = c8 + j;
      o[j] = (c < H_N) ? hidden[(size_t)b * H_N + c] : 0.f;
    }
  }
  f32x4 v0, v1;
#pragma unroll
  for (int j = 0; j < 4; ++j) { v0[j] = o[j]; v1[j] = o[4 + j]; }
  *(f32x4*)(tail + (size_t)b * TW + c8) = v0;
  *(f32x4*)(tail + (size_t)b * TW + c8 + 4) = v1;
}

// ---------------- pack U|W -> Wc, gld-linear physical order -----------------
__global__ __launch_bounds__(256) void pack_w_kernel(
    const float* __restrict__ U0, const float* __restrict__ U1,
    const float* __restrict__ U2, const float* __restrict__ U3,
    const float* __restrict__ W0, const float* __restrict__ W1,
    const float* __restrict__ W2, const float* __restrict__ W3,
    u16* __restrict__ Wc) {
  int idx = blockIdx.x * 256 + threadIdx.x;
  if (idx >= NKT * 2048) return;
  int t = idx >> 11;
  int j = idx & 2047;
  int pair = j >> 3, p = j & 7;
  int pl = p ^ (pair & 7);
  int n = pair * 2 + (pl >> 2);
  int s = pl & 3;
  int k0 = t * 32 + s * 8;
  bf16x8 ov;
  if (n >= 400) {
#pragma unroll
    for (int e = 0; e < 8; ++e) ov[e] = 0;
  } else {
    int g = n / 100;
    int r = n - g * 100;
    const float* U = (g == 0) ? U0 : (g == 1) ? U1 : (g == 2) ? U2 : U3;
    const float* W = (g == 0) ? W0 : (g == 1) ? W1 : (g == 2) ? W2 : W3;
    if (k0 + 8 <= D_N) {
      const float* pu = U + (size_t)r * D_N + k0;
      f32x4 v0 = *(const f32x4*)pu;
      f32x4 v1 = *(const f32x4*)(pu + 4);
#pragma unroll
      for (int e = 0; e < 4; ++e) { ov[e] = f2bf(v0[e]); ov[4 + e] = f2bf(v1[e]); }
    } else {
#pragma unroll
      for (int e = 0; e < 8; ++e) {
        int col = k0 + e - D_N;
        ov[e] = (col >= 0 && col < H_N) ? f2bf(W[(size_t)r * H_N + col]) : (short)0;
      }
    }
  }
  *(bf16x8*)(Wc + (size_t)idx * 8) = ov;
}

// ---------------- pack V_w -> V2, MFMA-native layout ------------------------
__global__ __launch_bounds__(256) void pack_vw_kernel(
    const float* __restrict__ Vw, u16* __restrict__ V2) {
  int idx = blockIdx.x * 256 + threadIdx.x;
  if (idx >= 500 * 256) return;
  int n16 = idx >> 8, r = idx & 255;
  int kk = r >> 6, q = r & 63;
  int h = q >> 4, lr = q & 15;
  int n = n16 * 16 + lr;
  int k0 = kk * 32 + h * 8;
  bf16x8 ov;
#pragma unroll
  for (int e = 0; e < 8; ++e) {
    int col = k0 + e;
    ov[e] = (col < H_N) ? f2bf(Vw[(size_t)n * H_N + col]) : (short)0;
  }
  *(bf16x8*)(V2 + (size_t)idx * 8) = ov;
}

// ---------------- gates GEMM: BM=64, BN=512, BK=32, splitK=4 ----------------
// R13 drain-only geometry + ONE change: the A-load for tile k+2 is issued
// AFTER body k's drain (into 2 rotating named slots), so at every vmcnt(0)
// the pending A-load is a full body old (~4000 cyc >> 900 HBM latency) and
// the drain only covers this body's L2 B-loads (covered by COMPUTE).
// Still drain-only: every wait is vmcnt(0)/lgkmcnt(0); slot WAR is a
// compiler-tracked register dependency. Race-free by construction.
__global__ __launch_bounds__(512, 4) void gates_gemm_kernel(
    const float* __restrict__ x, const float* __restrict__ tail,
    const u16* __restrict__ Wc, u16* __restrict__ Cp) {
  __shared__ __align__(16) u16 As[2][2048];     // 4 KB each, pair-XOR swizzled
  __shared__ __align__(16) u16 Bs[2][16384];    // 32 KB each, pre-swizzled src
  const int t = threadIdx.x;
  const int w = t >> 6, l = t & 63;
  const int bid = blockIdx.x;
  const int xcd = bid & 7;
  const int kz = xcd >> 1;
  const int bm = (bid >> 3) | ((xcd & 1) << 6);   // 0..127, bijective with kz
  const int t0 = kz * 64;
  const int tmax = t0 + 63;

  const int arow = t >> 3, ao = t & 7;
  const float* xrow = x + (size_t)(bm * 64 + arow) * D_N + ao * 4;
  const float* trow = tail + (size_t)(bm * 64 + arow) * TW + ao * 4;
  const int apair = arow >> 1;
  const int awr = apair * 64 + ((((arow & 1) << 2) | (ao >> 1)) ^ (apair & 7)) * 8
                  + (ao & 1) * 4;  // u16 units

  const int wn = w * 64;
  int aoff[2][2], boff[2][2];
#pragma unroll
  for (int kk = 0; kk < 2; ++kk)
#pragma unroll
    for (int i = 0; i < 2; ++i) {
      int rowa = i * 32 + (l & 31);
      int sa = kk * 2 + (l >> 5);
      int pa = rowa >> 1;
      aoff[kk][i] = pa * 64 + ((((rowa & 1) << 2) | sa) ^ (pa & 7)) * 8;
      int rowb = wn + i * 32 + (l & 31);
      int pb = rowb >> 1;
      boff[kk][i] = pb * 64 + ((((rowb & 1) << 2) | sa) ^ (pb & 7)) * 8;
    }

  f32x16 acc00 = (f32x16)0.f, acc01 = (f32x16)0.f;
  f32x16 acc10 = (f32x16)0.f, acc11 = (f32x16)0.f;

#define ASRC(tt) ((tt) < 250 ? xrow + (size_t)(tt) * 32 : trow + (size_t)((tt) - 250) * 32)
#define CLAMPT(tt) ((tt) > tmax ? tmax : (tt))
#define GLD_B(tt, buf)                                                         \
  _Pragma("unroll") for (int q = 0; q < 4; ++q)                                \
      __builtin_amdgcn_global_load_lds(                                        \
          (gp_t)(const void*)(Wc + ((size_t)(tt) * 2048 + t + q * 512) * 8),   \
          (lp_t)(void*)((u16*)Bs[buf] + (t + q * 512) * 8), 16, 0, 0);
#define DSW_A(buf, rv)                                                         \
  {                                                                            \
    short4v wv;                                                                \
    wv[0] = f2bf(rv[0]); wv[1] = f2bf(rv[1]);                                  \
    wv[2] = f2bf(rv[2]); wv[3] = f2bf(rv[3]);                                  \
    *(short4v*)((u16*)As[buf] + awr) = wv;                                     \
  }
#define COMPUTE(buf)                                                           \
  _Pragma("unroll") for (int kk = 0; kk < 2; ++kk) {                           \
    bf16x8 af0 = *(const bf16x8*)((const u16*)As[buf] + aoff[kk][0]);          \
    bf16x8 af1 = *(const bf16x8*)((const u16*)As[buf] + aoff[kk][1]);          \
    bf16x8 bv0 = *(const bf16x8*)((const u16*)Bs[buf] + boff[kk][0]);          \
    bf16x8 bv1 = *(const bf16x8*)((const u16*)Bs[buf] + boff[kk][1]);          \
    acc00 = __builtin_amdgcn_mfma_f32_32x32x16_bf16(af0, bv0, acc00, 0, 0, 0); \
    acc01 = __builtin_amdgcn_mfma_f32_32x32x16_bf16(af0, bv1, acc01, 0, 0, 0); \
    acc10 = __builtin_amdgcn_mfma_f32_32x32x16_bf16(af1, bv0, acc10, 0, 0, 0); \
    acc11 = __builtin_amdgcn_mfma_f32_32x32x16_bf16(af1, bv1, acc11, 0, 0, 0); \
  }
// body k (buf CB = tile k; SUSE holds A(k+1), loaded a full body ago;
// SDEF gets A(k+2), issued after the drain):
// GLD_B(k+1) | COMPUTE(k) | vmcnt(0) | DSW_A(SUSE) | load A(k+2)->SDEF |
// lgkmcnt(0) | barrier.
#define BODY(CB, tc, SUSE, SDEF)                                               \
  {                                                                            \
    GLD_B(CLAMPT((tc) + 1), (CB) ^ 1);                                         \
    __builtin_amdgcn_sched_barrier(0);                                         \
    COMPUTE(CB);                                                               \
    __builtin_amdgcn_sched_barrier(0);                                         \
    asm volatile("s_waitcnt vmcnt(0)" ::: "memory");                           \
    __builtin_amdgcn_sched_barrier(0);                                         \
    DSW_A((CB) ^ 1, SUSE);                                                     \
    SDEF = *(const f32x4*)ASRC(CLAMPT((tc) + 2));                              \
    __builtin_amdgcn_sched_barrier(0);                                         \
    asm volatile("s_waitcnt lgkmcnt(0)" ::: "memory");                         \
    __builtin_amdgcn_s_barrier();                                              \
  }

  // Prologue: A(t0)->LDS[0] (drained); B(t0)->LDS[0]; A(t0+1)->sB (in
  // flight across the barrier, consumed by body t0 after its drain).
  f32x4 sA, sB;
  {
    f32x4 r0 = *(const f32x4*)ASRC(t0);
    GLD_B(t0, 0);
    asm volatile("s_waitcnt vmcnt(0)" ::: "memory");
    DSW_A(0, r0);
    sB = *(const f32x4*)ASRC(t0 + 1);
    __builtin_amdgcn_sched_barrier(0);
    asm volatile("s_waitcnt lgkmcnt(0)" ::: "memory");
    __builtin_amdgcn_s_barrier();
  }

  for (int tt = t0; tt < t0 + 64; tt += 2) {
    BODY(0, tt,     sB, sA);
    BODY(1, tt + 1, sA, sB);
  }

  // epilogue: store acc to bf16 partial buffer kz
  u16* Cg = Cp + (size_t)kz * B_N * NG;
  const int lcol = l & 31, lhi = (l >> 5) * 4;
#pragma unroll
  for (int mi = 0; mi < 2; ++mi)
#pragma unroll
    for (int ni = 0; ni < 2; ++ni) {
      f32x16 a = (mi == 0) ? (ni == 0 ? acc00 : acc01)
                           : (ni == 0 ? acc10 : acc11);
#pragma unroll
      for (int reg = 0; reg < 16; ++reg) {
        int row = bm * 64 + mi * 32 + (reg & 3) + 8 * (reg >> 2) + lhi;
        Cg[(size_t)row * NG + wn + ni * 32 + lcol] = (u16)f2bf(a[reg]);
      }
    }
#undef BODY
#undef COMPUTE
#undef DSW_A
#undef GLD_B
#undef CLAMPT
#undef ASRC
}

// ---------------- fused act + logits + log_softmax (exact R13 version) ------
__global__ __launch_bounds__(1024, 4) void logits_lsm_kernel(
    const u16* __restrict__ gp, const float* __restrict__ c_in,
    const float* __restrict__ biu, const float* __restrict__ bfu,
    const float* __restrict__ bou, const float* __restrict__ bgu,
    const float* __restrict__ biw, const float* __restrict__ bfw,
    const float* __restrict__ bow, const float* __restrict__ bgw,
    const u16* __restrict__ V2, const float* __restrict__ Vb,
    float* __restrict__ h_out, float* __restrict__ c_out,
    float* __restrict__ out) {
  __shared__ u16 hs[32][128];
  __shared__ float red[16][32];
  __shared__ float lse_s[32];
  int t = threadIdx.x, w = t >> 6, l = t & 63;
  int lr = l & 15, hq = l >> 4;
  int rowbase = blockIdx.x * 32;

  // ---- phase 0: LSTM pointwise for our 32 rows ----
  if (t < 32 * 28) hs[t / 28][100 + t % 28] = 0;
  const size_t st = (size_t)B_N * NG;
  for (int i = t; i < 3200; i += 1024) {
    int b = i / 100, r = i - b * 100;
    int row = rowbase + b;
    const u16* g0 = gp + (size_t)row * NG;
    float gi = bf2f(g0[r]) + bf2f(g0[r + st]) + bf2f(g0[r + 2 * st]) +
               bf2f(g0[r + 3 * st]) + biu[r] + biw[r];
    float gf = bf2f(g0[r + 100]) + bf2f(g0[r + 100 + st]) +
               bf2f(g0[r + 100 + 2 * st]) + bf2f(g0[r + 100 + 3 * st]) +
               bfu[r] + bfw[r];
    float go = bf2f(g0[r + 200]) + bf2f(g0[r + 200 + st]) +
               bf2f(g0[r + 200 + 2 * st]) + bf2f(g0[r + 200 + 3 * st]) +
               bou[r] + bow[r];
    float gg = bf2f(g0[r + 300]) + bf2f(g0[r + 300 + st]) +
               bf2f(g0[r + 300 + 2 * st]) + bf2f(g0[r + 300 + 3 * st]) +
               bgu[r] + bgw[r];
    float it = 1.f / (1.f + __expf(-gi));
    float ft = 1.f / (1.f + __expf(-gf));
    float ot = 1.f / (1.f + __expf(-go));
    float gt = tanhf(gg);
    float ct = c_in[(size_t)row * H_N + r] * ft + gt * it;
    float ht = tanhf(ct) * ot;
    h_out[(size_t)row * H_N + r] = ht;
    c_out[(size_t)row * H_N + r] = ct;
    hs[b][r] = (u16)f2bf(ht);
  }
  __syncthreads();

  bf16x8 hf[2][4];
#pragma unroll
  for (int mi = 0; mi < 2; ++mi)
#pragma unroll
    for (int kk = 0; kk < 4; ++kk)
      hf[mi][kk] = *(const bf16x8*)(&hs[mi * 16 + lr][kk * 32 + hq * 8]);

// vp points at this wave's 64-col group; frag (ni,kk) at vp + (ni*4+kk)*512
#define VLD(vp, ni, kk) (*(const bf16x8*)((vp) + ((ni) * 4 + (kk)) * 512))
#define MF(accv, buf, kk)                                                      \
  _Pragma("unroll") for (int ni = 0; ni < 4; ++ni) {                           \
    accv[0][ni] = __builtin_amdgcn_mfma_f32_16x16x32_bf16(                     \
        hf[0][kk], buf[ni], accv[0][ni], 0, 0, 0);                             \
    accv[1][ni] = __builtin_amdgcn_mfma_f32_16x16x32_bf16(                     \
        hf[1][kk], buf[ni], accv[1][ni], 0, 0, 0);                             \
  }
#define GEMM_TILE(accv, vp)                                                    \
  {                                                                            \
    bf16x8 va[4], vbu[4];                                                      \
    _Pragma("unroll") for (int ni = 0; ni < 4; ++ni) va[ni] = VLD(vp, ni, 0);  \
    _Pragma("unroll") for (int ni = 0; ni < 4; ++ni) vbu[ni] = VLD(vp, ni, 1); \
    MF(accv, va, 0)                                                            \
    _Pragma("unroll") for (int ni = 0; ni < 4; ++ni) va[ni] = VLD(vp, ni, 2);  \
    MF(accv, vbu, 1)                                                           \
    _Pragma("unroll") for (int ni = 0; ni < 4; ++ni) vbu[ni] = VLD(vp, ni, 3); \
    MF(accv, va, 2)                                                            \
    MF(accv, vbu, 3)                                                           \
  }

  float s[8];
#pragma unroll
  for (int r = 0; r < 8; ++r) s[r] = 0.f;

  // ---- pass 1: sum of exp(logit - 8) ----
  for (int c = 0; c < 8; ++c) {
    int colbase = c * 1024 + w * 64;
    if (colbase >= V_N) continue;
    const u16* vp = V2 + (size_t)(colbase >> 4) * 2048 + l * 8;
    f32x4 acc[2][4];
#pragma unroll
    for (int mi = 0; mi < 2; ++mi)
#pragma unroll
      for (int ni = 0; ni < 4; ++ni) acc[mi][ni] = (f32x4)0.f;
    GEMM_TILE(acc, vp)
    float vb[4];
#pragma unroll
    for (int ni = 0; ni < 4; ++ni) vb[ni] = Vb[colbase + ni * 16 + lr];
#pragma unroll
    for (int r = 0; r < 8; ++r) {
      int mi = r >> 2, j = r & 3;
      float e = 0.f;
#pragma unroll
      for (int ni = 0; ni < 4; ++ni)
        e += __expf(acc[mi][ni][j] + vb[ni] - 8.f);
      s[r] += e;
    }
  }
#pragma unroll
  for (int off = 1; off < 16; off <<= 1)
#pragma unroll
    for (int r = 0; r < 8; ++r) s[r] += __shfl_xor(s[r], off, 64);

  if (lr == 0) {
#pragma unroll
    for (int r = 0; r < 8; ++r)
      red[w][(r >> 2) * 16 + hq * 4 + (r & 3)] = s[r];
  }
  __syncthreads();
  if (t < 32) {
    float S = 0.f;
#pragma unroll
    for (int ww = 0; ww < 16; ++ww) S += red[ww][t];
    lse_s[t] = 8.f + __logf(S);
  }
  __syncthreads();
  float lse_r[8];
#pragma unroll
  for (int r = 0; r < 8; ++r)
    lse_r[r] = lse_s[(r >> 2) * 16 + hq * 4 + (r & 3)];

  // ---- pass 2: recompute, subtract, store ----
  for (int c = 0; c < 8; ++c) {
    int colbase = c * 1024 + w * 64;
    if (colbase >= V_N) continue;
    const u16* vp = V2 + (size_t)(colbase >> 4) * 2048 + l * 8;
    f32x4 acc[2][4];
#pragma unroll
    for (int mi = 0; mi < 2; ++mi)
#pragma unroll
      for (int ni = 0; ni < 4; ++ni) acc[mi][ni] = (f32x4)0.f;
    GEMM_TILE(acc, vp)
    float vb[4];
#pragma unroll
    for (int ni = 0; ni < 4; ++ni) vb[ni] = Vb[colbase + ni * 16 + lr];
#pragma unroll
    for (int mi = 0; mi < 2; ++mi)
#pragma unroll
      for (int j = 0; j < 4; ++j) {
        size_t gr = (size_t)(rowbase + mi * 16 + hq * 4 + j);
#pragma unroll
        for (int ni = 0; ni < 4; ++ni)
          out[gr * V_N + colbase + ni * 16 + lr] =
              acc[mi][ni][j] + vb[ni] - lse_r[mi * 4 + j];
      }
  }
#undef GEMM_TILE
#undef MF
#undef VLD
}

extern "C" void kernel_launch(void* const* d_in, const int* in_sizes, int n_in,
                              void* d_out, int out_size, void* d_ws,
                              size_t ws_size, hipStream_t stream) {
  const float* x      = (const float*)d_in[0];
  const float* hidden = (const float*)d_in[1];
  const float* c_in   = (const float*)d_in[2];
  const float* Ui = (const float*)d_in[3];
  const float* Uf = (const float*)d_in[4];
  const float* Uo = (const float*)d_in[5];
  const float* Ug = (const float*)d_in[6];
  const float* Wi = (const float*)d_in[7];
  const float* Wf = (const float*)d_in[8];
  const float* Wo = (const float*)d_in[9];
  const float* Wg = (const float*)d_in[10];
  const float* Vw = (const float*)d_in[11];
  const float* Uib = (const float*)d_in[12];
  const float* Ufb = (const float*)d_in[13];
  const float* Uob = (const float*)d_in[14];
  const float* Ugb = (const float*)d_in[15];
  const float* Wib = (const float*)d_in[16];
  const float* Wfb = (const float*)d_in[17];
  const float* Wob = (const float*)d_in[18];
  const float* Wgb = (const float*)d_in[19];
  const float* Vb  = (const float*)d_in[20];

  float* out   = (float*)d_out;
  float* h_out = out + (size_t)B_N * V_N;
  float* c_out = h_out + (size_t)B_N * H_N;

  char* ws = (char*)d_ws;
  float* tailf = (float*)ws;  ws += (size_t)B_N * TW * 4;        // 6.3 MB
  u16* Wc = (u16*)ws;         ws += (size_t)NKT * 2048 * 16;     // 8.4 MB
  u16* V2 = (u16*)ws;         ws += (size_t)500 * 256 * 16;      // 2.0 MB
  u16* gates_p = (u16*)ws;    ws += (size_t)4 * B_N * NG * 2;    // 33.6 MB

  pack_tail_kernel<<<dim3(768), dim3(256), 0, stream>>>(hidden, tailf);
  pack_w_kernel<<<dim3(2048), dim3(256), 0, stream>>>(Ui, Uf, Uo, Ug,
                                                      Wi, Wf, Wo, Wg, Wc);
  pack_vw_kernel<<<dim3(500), dim3(256), 0, stream>>>(Vw, V2);

  gates_gemm_kernel<<<dim3(512), dim3(512), 0, stream>>>(
      x, tailf, Wc, gates_p);

  logits_lsm_kernel<<<dim3(256), dim3(1024), 0, stream>>>(
      gates_p, c_in, Uib, Ufb, Uob, Ugb, Wib, Wfb, Wob, Wgb,
      V2, Vb, h_out, c_out, out);
}